// Round 6
// baseline (940.067 us; speedup 1.0000x reference)
//
#include <hip/hip_runtime.h>
#include <hip/hip_bf16.h>

#define N_NODES 65536
#define D_IN 1024
#define D_HID 64
#define N_CLS 32
#define NBUK 256   // buckets keyed by dst >> 8
#define NSB 256    // scatter/hist blocks (4096 edges each)

typedef short short8 __attribute__((ext_vector_type(8)));
typedef float floatx4 __attribute__((ext_vector_type(4)));

// ---------- helpers ----------
__device__ __forceinline__ unsigned short f2bf(float f) {
  union { float f; unsigned u; } cv; cv.f = f;
  unsigned r = (cv.u + 0x7FFFu + ((cv.u >> 16) & 1u)) >> 16;
  return (unsigned short)r;
}
__device__ __forceinline__ float2 bf2f2(unsigned v) {
  union { unsigned u; float f; } a, b;
  a.u = v << 16;
  b.u = v & 0xFFFF0000u;
  return make_float2(a.f, b.f);  // (elem 2l, elem 2l+1)
}

// ---------- pass 1: histogram by dst>>8 (blocks 0..255, H block-major)
//            + W1^T -> bf16 (blocks 256..511) ----------
__global__ void k_hist_w1t(const int* __restrict__ dst, int* __restrict__ H,
                           const float* __restrict__ w1, unsigned short* __restrict__ w1t,
                           int e4) {
  int b = blockIdx.x, t = threadIdx.x;
  if (b >= NSB) {
    int i = (b - NSB) * 256 + t;  // [0, 65536)
    int k = i / D_HID, n = i % D_HID;
    w1t[n * D_IN + k] = f2bf(w1[i]);
    return;
  }
  __shared__ int hist[NBUK];
  hist[t] = 0;
  __syncthreads();
  const int4* d4 = (const int4*)dst + b * 1024;
#pragma unroll
  for (int p = 0; p < 4; p++) {
    int i4 = b * 1024 + p * 256 + t;
    if (i4 < e4) {
      int4 d = d4[p * 256 + t];
      atomicAdd(&hist[d.x >> 8], 1);
      atomicAdd(&hist[d.y >> 8], 1);
      atomicAdd(&hist[d.z >> 8], 1);
      atomicAdd(&hist[d.w >> 8], 1);
    }
  }
  __syncthreads();
  H[b * NBUK + t] = hist[t];  // block-major: coalesced
}

// ---------- pass 2a: per-bin exclusive scan over 256 blocks -> Hs (bin-major) ----------
__global__ void k_scan_bin(const int* __restrict__ H, int* __restrict__ Hs,
                           int* __restrict__ btot) {
  int bin = blockIdx.x, t = threadIdx.x;
  int v = H[t * NBUK + bin];
  __shared__ int s[256];
  s[t] = v;
  __syncthreads();
  for (int off = 1; off < 256; off <<= 1) {
    int x = (t >= off) ? s[t - off] : 0;
    __syncthreads();
    s[t] += x;
    __syncthreads();
  }
  Hs[bin * NSB + t] = s[t] - v;
  if (t == 255) btot[bin] = s[255];
}

// ---------- pass 2b: scan bucket totals -> bucket base offsets ----------
__global__ void k_scan_tot(const int* __restrict__ btot, int* __restrict__ btoff) {
  __shared__ int s[256];
  int t = threadIdx.x;
  int v = btot[t];
  s[t] = v;
  __syncthreads();
  for (int off = 1; off < 256; off <<= 1) {
    int x = (t >= off) ? s[t - off] : 0;
    __syncthreads();
    s[t] += x;
    __syncthreads();
  }
  btoff[t] = s[t] - v;
}

// ---------- pass 3 (fused): LDS-staged bucket scatter (blocks 0..255)
//            + GEMM1 unscaled (blocks 256..1279) ----------
__global__ __launch_bounds__(256) void k_scatter_gemm1(
    const int* __restrict__ dst, const int* __restrict__ src,
    const int* __restrict__ Hs, const int* __restrict__ btoff,
    unsigned* __restrict__ pk, int e4,
    const float* __restrict__ x, const unsigned short* __restrict__ w1t,
    unsigned short* __restrict__ xw1s) {
  if (blockIdx.x < NSB) {
    __shared__ int cnt[NBUK], sc[NBUK], cur[NBUK], base2[NBUK];
    __shared__ unsigned stage[4096];
    int b = blockIdx.x, t = threadIdx.x;
    cnt[t] = 0;
    __syncthreads();
    const int4* d4 = (const int4*)dst + b * 1024;
    const int4* s4 = (const int4*)src + b * 1024;
    int4 dv[4], sv[4]; bool ok[4];
#pragma unroll
    for (int p = 0; p < 4; p++) {
      int i4 = b * 1024 + p * 256 + t;
      ok[p] = i4 < e4;
      if (ok[p]) {
        dv[p] = d4[p * 256 + t];
        sv[p] = s4[p * 256 + t];
        atomicAdd(&cnt[dv[p].x >> 8], 1);
        atomicAdd(&cnt[dv[p].y >> 8], 1);
        atomicAdd(&cnt[dv[p].z >> 8], 1);
        atomicAdd(&cnt[dv[p].w >> 8], 1);
      }
    }
    __syncthreads();
    int c = cnt[t];
    sc[t] = c;
    __syncthreads();
    for (int off = 1; off < 256; off <<= 1) {
      int xv = (t >= off) ? sc[t - off] : 0;
      __syncthreads();
      sc[t] += xv;
      __syncthreads();
    }
    int excl = sc[t] - c;
    cur[t] = excl;
    base2[t] = btoff[t] + Hs[t * NSB + b] - excl;  // pk dest = base2[bin] + stagedIdx
    __syncthreads();
    int tot = sc[255];
#pragma unroll
    for (int p = 0; p < 4; p++) {
      if (ok[p]) {
        int d[4] = {dv[p].x, dv[p].y, dv[p].z, dv[p].w};
        int s[4] = {sv[p].x, sv[p].y, sv[p].z, sv[p].w};
#pragma unroll
        for (int j = 0; j < 4; j++) {
          int pos = atomicAdd(&cur[d[j] >> 8], 1);
          stage[pos] = ((unsigned)d[j] << 16) | (unsigned)s[j];
        }
      }
    }
    __syncthreads();
    for (int i = t; i < tot; i += 256) {
      unsigned u = stage[i];
      pk[base2[u >> 24] + i] = u;
    }
    return;
  }
  // ----- GEMM1: xw1 = x @ W1 (UNSCALED), bf16 out; 16 rows/wave -----
  int wave = threadIdx.x >> 6;
  int lane = threadIdx.x & 63;
  int quad = lane >> 4;
  int l16 = lane & 15;
  int rowbase = (blockIdx.x - NSB) * 64 + wave * 16;
  const float* xrow = x + (size_t)(rowbase + l16) * D_IN + quad * 8;
  const unsigned short* bbase = w1t + quad * 8;
  floatx4 acc[4];
#pragma unroll
  for (int nt = 0; nt < 4; nt++) acc[nt] = (floatx4){0.f, 0.f, 0.f, 0.f};
  float4 p0 = *(const float4*)(xrow + 0);
  float4 p1 = *(const float4*)(xrow + 4);
  float4 p2 = *(const float4*)(xrow + 32);
  float4 p3 = *(const float4*)(xrow + 36);
  short8 bf0[4], bf1[4];
#pragma unroll
  for (int nt = 0; nt < 4; nt++) {
    const unsigned short* bp = bbase + (size_t)(nt * 16 + l16) * D_IN;
    bf0[nt] = *(const short8*)(bp);
    bf1[nt] = *(const short8*)(bp + 32);
  }
  for (int k0 = 0; k0 < D_IN; k0 += 64) {
    float4 c0 = p0, c1 = p1, c2 = p2, c3 = p3;
    int kn = (k0 + 64 < D_IN) ? k0 + 64 : k0;
    p0 = *(const float4*)(xrow + kn);
    p1 = *(const float4*)(xrow + kn + 4);
    p2 = *(const float4*)(xrow + kn + 32);
    p3 = *(const float4*)(xrow + kn + 36);
    float av0[8] = {c0.x, c0.y, c0.z, c0.w, c1.x, c1.y, c1.z, c1.w};
    float av1[8] = {c2.x, c2.y, c2.z, c2.w, c3.x, c3.y, c3.z, c3.w};
    short8 af0, af1;
    unsigned* u0 = (unsigned*)&af0;
    unsigned* u1 = (unsigned*)&af1;
#pragma unroll
    for (int j = 0; j < 4; j++) {
      asm("v_cvt_pk_bf16_f32 %0, %1, %2" : "=v"(u0[j]) : "v"(av0[2 * j]), "v"(av0[2 * j + 1]));
      asm("v_cvt_pk_bf16_f32 %0, %1, %2" : "=v"(u1[j]) : "v"(av1[2 * j]), "v"(av1[2 * j + 1]));
    }
#pragma unroll
    for (int nt = 0; nt < 4; nt++)
      acc[nt] = __builtin_amdgcn_mfma_f32_16x16x32_bf16(af0, bf0[nt], acc[nt], 0, 0, 0);
#pragma unroll
    for (int nt = 0; nt < 4; nt++)
      bf0[nt] = *(const short8*)(bbase + (size_t)(nt * 16 + l16) * D_IN + kn);
#pragma unroll
    for (int nt = 0; nt < 4; nt++)
      acc[nt] = __builtin_amdgcn_mfma_f32_16x16x32_bf16(af1, bf1[nt], acc[nt], 0, 0, 0);
#pragma unroll
    for (int nt = 0; nt < 4; nt++)
      bf1[nt] = *(const short8*)(bbase + (size_t)(nt * 16 + l16) * D_IN + kn + 32);
  }
#pragma unroll
  for (int r = 0; r < 4; r++) {
    int row = rowbase + quad * 4 + r;
#pragma unroll
    for (int nt = 0; nt < 4; nt++)
      xw1s[(size_t)row * D_HID + nt * 16 + l16] = f2bf(acc[nt][r]);
  }
}

// ---------- pass 4: per-bucket degree -> dinv (no CSR scatter needed) ----------
__global__ void k_deg(const unsigned* __restrict__ pk, const int* __restrict__ btoff,
                      const int* __restrict__ btot, float* __restrict__ dinv) {
  __shared__ int cnt[NBUK];
  int bin = blockIdx.x, t = threadIdx.x;
  cnt[t] = 0;
  __syncthreads();
  int beg = btoff[bin], len = btot[bin];
  for (int i = t; i < len; i += 256)
    atomicAdd(&cnt[(pk[beg + i] >> 16) & 255], 1);
  __syncthreads();
  dinv[bin * 256 + t] = rsqrtf((float)(cnt[t] + 1));
}

// ---------- agg1 + gemm2: bucket-parallel, LDS accumulation ----------
// one block per bucket; hbuf[256][64] f32 accumulates sum_{src} dinv[src]*xw1[src]
__global__ __launch_bounds__(512) void k_agg1b(const unsigned* __restrict__ pk,
    const int* __restrict__ btoff, const int* __restrict__ btot,
    const unsigned* __restrict__ xw1s2, const float* __restrict__ dinv,
    const float* __restrict__ b1, const float* __restrict__ w2,
    unsigned short* __restrict__ xw2s) {
  __shared__ float hbuf[256][64];          // 64KB
  __shared__ float w2s[D_HID * N_CLS];     // 8KB
  int t = threadIdx.x, bin = blockIdx.x;
  for (int i = t; i < D_HID * N_CLS; i += 512) w2s[i] = w2[i];
  for (int i = t; i < 256 * 64; i += 512) ((float*)hbuf)[i] = 0.f;
  __syncthreads();
  int beg = btoff[bin], len = btot[bin];
  int hw = t >> 5;      // half-wave id 0..15
  int l = t & 31;       // lane in half-wave (dims 2l, 2l+1)
  // stream edges coalesced; 8 gathers in flight per half-wave
  for (int e0 = hw * 8; e0 < len; e0 += 128) {
    unsigned u[8]; bool ok[8];
#pragma unroll
    for (int j = 0; j < 8; j++) {
      int e = e0 + j;
      ok[j] = e < len;
      u[j] = pk[beg + (ok[j] ? e : 0)];
    }
    float dv[8];
#pragma unroll
    for (int j = 0; j < 8; j++) dv[j] = dinv[u[j] & 0xFFFFu];
#pragma unroll
    for (int j = 0; j < 8; j++) {
      float2 v = bf2f2(xw1s2[(size_t)(u[j] & 0xFFFFu) * 32 + l]);
      if (ok[j]) {
        int d = (u[j] >> 16) & 255;
        atomicAdd(&hbuf[d][2 * l], dv[j] * v.x);
        atomicAdd(&hbuf[d][2 * l + 1], dv[j] * v.y);
      }
    }
  }
  __syncthreads();
  // finish: h = relu(dd*(sum + dd*self) + b1), in place
  for (int i = t; i < 256 * 32; i += 512) {
    int n = i >> 5, ll = i & 31;
    int node = bin * 256 + n;
    float dd = dinv[node];
    float2 self = bf2f2(xw1s2[(size_t)node * 32 + ll]);
    float2 bb = ((const float2*)b1)[ll];
    float hx = dd * (hbuf[n][2 * ll] + dd * self.x) + bb.x;
    float hy = dd * (hbuf[n][2 * ll + 1] + dd * self.y) + bb.y;
    hbuf[n][2 * ll] = hx > 0.f ? hx : 0.f;
    hbuf[n][2 * ll + 1] = hy > 0.f ? hy : 0.f;
  }
  __syncthreads();
  // gemm2: p[n][c] = sum_k h[n][k]*w2[k][c]; store bf16(p*dd)
  for (int i = t; i < 256 * 32; i += 512) {
    int n = i >> 5, c = i & 31;
    int node = bin * 256 + n;
    float p = 0.f;
#pragma unroll
    for (int k = 0; k < 64; k++) p += hbuf[n][k] * w2s[k * N_CLS + c];
    xw2s[(size_t)node * N_CLS + c] = f2bf(p * dinv[node]);
  }
}

// ---------- agg2 + log_softmax: bucket-parallel, LDS accumulation ----------
__global__ __launch_bounds__(512) void k_agg2b(const unsigned* __restrict__ pk,
    const int* __restrict__ btoff, const int* __restrict__ btot,
    const unsigned* __restrict__ xw2s2, const float* __restrict__ dinv,
    const float* __restrict__ b2, float* __restrict__ out) {
  __shared__ float obuf[256][32];          // 32KB
  int t = threadIdx.x, bin = blockIdx.x;
  for (int i = t; i < 256 * 32; i += 512) ((float*)obuf)[i] = 0.f;
  __syncthreads();
  int beg = btoff[bin], len = btot[bin];
  int qw = t >> 4;      // quarter-wave id 0..31
  int l = t & 15;       // lane in quarter-wave (cls 2l, 2l+1)
  for (int e0 = qw * 8; e0 < len; e0 += 256) {
    unsigned u[8]; bool ok[8];
#pragma unroll
    for (int j = 0; j < 8; j++) {
      int e = e0 + j;
      ok[j] = e < len;
      u[j] = pk[beg + (ok[j] ? e : 0)];
    }
#pragma unroll
    for (int j = 0; j < 8; j++) {
      float2 v = bf2f2(xw2s2[(size_t)(u[j] & 0xFFFFu) * 16 + l]);
      if (ok[j]) {
        int d = (u[j] >> 16) & 255;
        atomicAdd(&obuf[d][2 * l], v.x);
        atomicAdd(&obuf[d][2 * l + 1], v.y);
      }
    }
  }
  __syncthreads();
  // finish: logits + log_softmax per node (16 lanes per node, 2 cls each)
  for (int i = t; i < 256 * 16; i += 512) {
    int n = i >> 4, ll = i & 15;
    int node = bin * 256 + n;
    float dd = dinv[node];
    float2 self = bf2f2(xw2s2[(size_t)node * 16 + ll]);
    float2 bb = ((const float2*)b2)[ll];
    float lx = dd * (obuf[n][2 * ll] + self.x) + bb.x;
    float ly = dd * (obuf[n][2 * ll + 1] + self.y) + bb.y;
    float m = fmaxf(lx, ly);
#pragma unroll
    for (int o = 8; o > 0; o >>= 1) m = fmaxf(m, __shfl_xor(m, o));
    float s2 = __expf(lx - m) + __expf(ly - m);
#pragma unroll
    for (int o = 8; o > 0; o >>= 1) s2 += __shfl_xor(s2, o);
    float lse = m + __logf(s2);
    ((float2*)out)[(size_t)node * 16 + ll] = make_float2(lx - lse, ly - lse);
  }
}

extern "C" void kernel_launch(void* const* d_in, const int* in_sizes, int n_in,
                              void* d_out, int out_size, void* d_ws, size_t ws_size,
                              hipStream_t stream) {
  (void)n_in; (void)out_size; (void)ws_size;
  const float* x  = (const float*)d_in[0];
  const int*   ei = (const int*)d_in[1];
  const float* w1 = (const float*)d_in[2];
  const float* b1 = (const float*)d_in[3];
  const float* w2 = (const float*)d_in[4];
  const float* b2 = (const float*)d_in[5];
  float* out = (float*)d_out;
  int e = in_sizes[1] / 2;
  const int* src = ei;
  const int* dst = ei + e;

  char* ws = (char*)d_ws;
  int* H              = (int*)(ws + 0x0000000);           // 256KB (block-major)
  int* Hs             = (int*)(ws + 0x0040000);           // 256KB (bin-major, scanned)
  int* btot           = (int*)(ws + 0x0080000);           // 1KB
  int* btoff          = (int*)(ws + 0x0080400);           // 1KB
  float* dinv         = (float*)(ws + 0x00D0000);         // 256KB
  unsigned* pk        = (unsigned*)(ws + 0x0200000);      // 4MB (bucket-sorted packed edges)
  unsigned short* w1t = (unsigned short*)(ws + 0x0A00000);// 128KB
  unsigned short* xw1s= (unsigned short*)(ws + 0x0A20000);// 8MB (bf16, UNSCALED)
  unsigned short* xw2s= (unsigned short*)(ws + 0x1220000);// 4MB (bf16)

  int e4 = e / 4;
  k_hist_w1t     <<<NSB + 256, 256, 0, stream>>>(dst, H, w1, w1t, e4);
  k_scan_bin     <<<NBUK, 256, 0, stream>>>(H, Hs, btot);
  k_scan_tot     <<<1, 256, 0, stream>>>(btot, btoff);
  k_scatter_gemm1<<<NSB + 1024, 256, 0, stream>>>(dst, src, Hs, btoff, pk, e4,
                                                  x, w1t, xw1s);
  k_deg          <<<NBUK, 256, 0, stream>>>(pk, btoff, btot, dinv);
  k_agg1b        <<<NBUK, 512, 0, stream>>>(pk, btoff, btot, (const unsigned*)xw1s,
                                            dinv, b1, w2, xw2s);
  k_agg2b        <<<NBUK, 512, 0, stream>>>(pk, btoff, btot, (const unsigned*)xw2s,
                                            dinv, b2, out);
}

// Round 7
// 600.331 us; speedup vs baseline: 1.5659x; 1.5659x over previous
//
#include <hip/hip_runtime.h>
#include <hip/hip_bf16.h>

#define N_NODES 65536
#define D_IN 1024
#define D_HID 64
#define N_CLS 32
#define NBUK 256   // buckets keyed by dst >> 8
#define NSB 256    // scatter/hist blocks (4096 edges each)

typedef short short8 __attribute__((ext_vector_type(8)));
typedef float floatx4 __attribute__((ext_vector_type(4)));

// ---------- helpers ----------
__device__ __forceinline__ unsigned short f2bf(float f) {
  union { float f; unsigned u; } cv; cv.f = f;
  unsigned r = (cv.u + 0x7FFFu + ((cv.u >> 16) & 1u)) >> 16;
  return (unsigned short)r;
}
__device__ __forceinline__ float2 bf2f2(unsigned v) {
  union { unsigned u; float f; } a, b;
  a.u = v << 16;
  b.u = v & 0xFFFF0000u;
  return make_float2(a.f, b.f);  // (elem 2l, elem 2l+1)
}

// ---------- pass 1: histogram by dst>>8 (blocks 0..255, H block-major)
//            + W1^T -> bf16 (blocks 256..511) ----------
__global__ void k_hist_w1t(const int* __restrict__ dst, int* __restrict__ H,
                           const float* __restrict__ w1, unsigned short* __restrict__ w1t,
                           int e4) {
  int b = blockIdx.x, t = threadIdx.x;
  if (b >= NSB) {
    int i = (b - NSB) * 256 + t;  // [0, 65536)
    int k = i / D_HID, n = i % D_HID;
    w1t[n * D_IN + k] = f2bf(w1[i]);
    return;
  }
  __shared__ int hist[NBUK];
  hist[t] = 0;
  __syncthreads();
  const int4* d4 = (const int4*)dst + b * 1024;
#pragma unroll
  for (int p = 0; p < 4; p++) {
    int i4 = b * 1024 + p * 256 + t;
    if (i4 < e4) {
      int4 d = d4[p * 256 + t];
      atomicAdd(&hist[d.x >> 8], 1);
      atomicAdd(&hist[d.y >> 8], 1);
      atomicAdd(&hist[d.z >> 8], 1);
      atomicAdd(&hist[d.w >> 8], 1);
    }
  }
  __syncthreads();
  H[b * NBUK + t] = hist[t];  // block-major: coalesced
}

// ---------- pass 2a: per-bin exclusive scan over 256 blocks -> Hs (bin-major) ----------
__global__ void k_scan_bin(const int* __restrict__ H, int* __restrict__ Hs,
                           int* __restrict__ btot) {
  int bin = blockIdx.x, t = threadIdx.x;
  int v = H[t * NBUK + bin];
  __shared__ int s[256];
  s[t] = v;
  __syncthreads();
  for (int off = 1; off < 256; off <<= 1) {
    int x = (t >= off) ? s[t - off] : 0;
    __syncthreads();
    s[t] += x;
    __syncthreads();
  }
  Hs[bin * NSB + t] = s[t] - v;
  if (t == 255) btot[bin] = s[255];
}

// ---------- pass 2b: scan bucket totals -> bucket base offsets ----------
__global__ void k_scan_tot(const int* __restrict__ btot, int* __restrict__ btoff,
                           int* __restrict__ rowptr, int e) {
  __shared__ int s[256];
  int t = threadIdx.x;
  int v = btot[t];
  s[t] = v;
  __syncthreads();
  for (int off = 1; off < 256; off <<= 1) {
    int x = (t >= off) ? s[t - off] : 0;
    __syncthreads();
    s[t] += x;
    __syncthreads();
  }
  btoff[t] = s[t] - v;
  if (t == 0) rowptr[N_NODES] = e;
}

// ---------- pass 3: LDS-staged bucket scatter (256 blocks) ----------
__global__ __launch_bounds__(256) void k_scatter(
    const int* __restrict__ dst, const int* __restrict__ src,
    const int* __restrict__ Hs, const int* __restrict__ btoff,
    unsigned* __restrict__ pk, int e4) {
  __shared__ int cnt[NBUK], sc[NBUK], cur[NBUK], base2[NBUK];
  __shared__ unsigned stage[4096];
  int b = blockIdx.x, t = threadIdx.x;
  cnt[t] = 0;
  __syncthreads();
  const int4* d4 = (const int4*)dst + b * 1024;
  const int4* s4 = (const int4*)src + b * 1024;
  int4 dv[4], sv[4]; bool ok[4];
#pragma unroll
  for (int p = 0; p < 4; p++) {
    int i4 = b * 1024 + p * 256 + t;
    ok[p] = i4 < e4;
    if (ok[p]) {
      dv[p] = d4[p * 256 + t];
      sv[p] = s4[p * 256 + t];
      atomicAdd(&cnt[dv[p].x >> 8], 1);
      atomicAdd(&cnt[dv[p].y >> 8], 1);
      atomicAdd(&cnt[dv[p].z >> 8], 1);
      atomicAdd(&cnt[dv[p].w >> 8], 1);
    }
  }
  __syncthreads();
  int c = cnt[t];
  sc[t] = c;
  __syncthreads();
  for (int off = 1; off < 256; off <<= 1) {
    int xv = (t >= off) ? sc[t - off] : 0;
    __syncthreads();
    sc[t] += xv;
    __syncthreads();
  }
  int excl = sc[t] - c;
  cur[t] = excl;
  base2[t] = btoff[t] + Hs[t * NSB + b] - excl;  // pk dest = base2[bin] + stagedIdx
  __syncthreads();
  int tot = sc[255];
#pragma unroll
  for (int p = 0; p < 4; p++) {
    if (ok[p]) {
      int d[4] = {dv[p].x, dv[p].y, dv[p].z, dv[p].w};
      int s[4] = {sv[p].x, sv[p].y, sv[p].z, sv[p].w};
#pragma unroll
      for (int j = 0; j < 4; j++) {
        int pos = atomicAdd(&cur[d[j] >> 8], 1);
        stage[pos] = ((unsigned)d[j] << 16) | (unsigned)s[j];
      }
    }
  }
  __syncthreads();
  for (int i = t; i < tot; i += 256) {
    unsigned u = stage[i];
    pk[base2[u >> 24] + i] = u;
  }
}

// ---------- pass 4: per-bucket local CSR (rowptr, dinv, csr_src) ----------
__global__ void k_bucket_csr(const unsigned* __restrict__ pk, const int* __restrict__ btoff,
                             const int* __restrict__ btot, int* __restrict__ rowptr,
                             int* __restrict__ csr_src, float* __restrict__ dinv) {
  __shared__ int cnt[NBUK], sc[NBUK], cur[NBUK];
  int bin = blockIdx.x, t = threadIdx.x;
  cnt[t] = 0;
  __syncthreads();
  int beg = btoff[bin], len = btot[bin];
  for (int i = t; i < len; i += 256)
    atomicAdd(&cnt[(pk[beg + i] >> 16) & 255], 1);
  __syncthreads();
  int c = cnt[t];
  sc[t] = c;
  __syncthreads();
  for (int off = 1; off < 256; off <<= 1) {
    int x = (t >= off) ? sc[t - off] : 0;
    __syncthreads();
    sc[t] += x;
    __syncthreads();
  }
  int excl = sc[t] - c;
  int node = bin * 256 + t;
  rowptr[node] = beg + excl;
  dinv[node] = rsqrtf((float)(c + 1));
  cur[t] = excl;
  __syncthreads();
  for (int i = t; i < len; i += 256) {
    unsigned u = pk[beg + i];
    int p = atomicAdd(&cur[(u >> 16) & 255], 1);
    csr_src[beg + p] = (int)(u & 0xFFFFu);
  }
}

// ---------- GEMM1: xw1 = x @ W1 (UNSCALED), bf16 out; depth-2 A prefetch ----------
// MEASUREMENT: grid doubled; blocks >=1024 redo the same rows (idempotent writes)
// so the dispatch duration = 2x true gemm1 cost -> crosses the 158us top-5 floor.
#define GCHUNK(PA, KC) do {                                                    \
    float4 c0 = PA[0], c1 = PA[1], c2 = PA[2], c3 = PA[3];                     \
    if ((KC) + 128 < D_IN) {                                                   \
      PA[0] = *(const float4*)(xrow + (KC) + 128);                             \
      PA[1] = *(const float4*)(xrow + (KC) + 132);                             \
      PA[2] = *(const float4*)(xrow + (KC) + 160);                             \
      PA[3] = *(const float4*)(xrow + (KC) + 164);                             \
    }                                                                          \
    int kb = ((KC) + 64 < D_IN) ? (KC) + 64 : (KC);                            \
    float av0[8] = {c0.x, c0.y, c0.z, c0.w, c1.x, c1.y, c1.z, c1.w};           \
    float av1[8] = {c2.x, c2.y, c2.z, c2.w, c3.x, c3.y, c3.z, c3.w};           \
    short8 af0, af1;                                                           \
    unsigned* u0 = (unsigned*)&af0;                                            \
    unsigned* u1 = (unsigned*)&af1;                                            \
    _Pragma("unroll") for (int j = 0; j < 4; j++) {                            \
      asm("v_cvt_pk_bf16_f32 %0, %1, %2"                                       \
          : "=v"(u0[j]) : "v"(av0[2 * j]), "v"(av0[2 * j + 1]));               \
      asm("v_cvt_pk_bf16_f32 %0, %1, %2"                                       \
          : "=v"(u1[j]) : "v"(av1[2 * j]), "v"(av1[2 * j + 1]));               \
    }                                                                          \
    _Pragma("unroll") for (int nt = 0; nt < 4; nt++)                           \
      acc[nt] = __builtin_amdgcn_mfma_f32_16x16x32_bf16(af0, bf0[nt], acc[nt], 0, 0, 0); \
    _Pragma("unroll") for (int nt = 0; nt < 4; nt++)                           \
      bf0[nt] = *(const short8*)(bbase + (size_t)(nt * 16 + l16) * D_IN + kb); \
    _Pragma("unroll") for (int nt = 0; nt < 4; nt++)                           \
      acc[nt] = __builtin_amdgcn_mfma_f32_16x16x32_bf16(af1, bf1[nt], acc[nt], 0, 0, 0); \
    _Pragma("unroll") for (int nt = 0; nt < 4; nt++)                           \
      bf1[nt] = *(const short8*)(bbase + (size_t)(nt * 16 + l16) * D_IN + kb + 32); \
  } while (0)

__global__ __launch_bounds__(256) void k_gemm1(
    const float* __restrict__ x, const unsigned short* __restrict__ w1t,
    unsigned short* __restrict__ xw1s) {
  int rb = blockIdx.x;
  if (rb >= 1024) rb -= 1024;  // measurement duplicate: same rows, same bytes
  int wave = threadIdx.x >> 6;
  int lane = threadIdx.x & 63;
  int quad = lane >> 4;
  int l16 = lane & 15;
  int rowbase = rb * 64 + wave * 16;
  const float* xrow = x + (size_t)(rowbase + l16) * D_IN + quad * 8;
  const unsigned short* bbase = w1t + quad * 8;
  floatx4 acc[4];
#pragma unroll
  for (int nt = 0; nt < 4; nt++) acc[nt] = (floatx4){0.f, 0.f, 0.f, 0.f};
  // prologue: chunks 0 and 1 of A in flight, chunk-0 B fragments
  float4 pa0[4], pa1[4];
  pa0[0] = *(const float4*)(xrow + 0);
  pa0[1] = *(const float4*)(xrow + 4);
  pa0[2] = *(const float4*)(xrow + 32);
  pa0[3] = *(const float4*)(xrow + 36);
  pa1[0] = *(const float4*)(xrow + 64);
  pa1[1] = *(const float4*)(xrow + 68);
  pa1[2] = *(const float4*)(xrow + 96);
  pa1[3] = *(const float4*)(xrow + 100);
  short8 bf0[4], bf1[4];
#pragma unroll
  for (int nt = 0; nt < 4; nt++) {
    const unsigned short* bp = bbase + (size_t)(nt * 16 + l16) * D_IN;
    bf0[nt] = *(const short8*)(bp);
    bf1[nt] = *(const short8*)(bp + 32);
  }
#pragma unroll
  for (int k0 = 0; k0 < D_IN; k0 += 128) {
    GCHUNK(pa0, k0);
    GCHUNK(pa1, k0 + 64);
  }
#pragma unroll
  for (int r = 0; r < 4; r++) {
    int row = rowbase + quad * 4 + r;
#pragma unroll
    for (int nt = 0; nt < 4; nt++)
      xw1s[(size_t)row * D_HID + nt * 16 + l16] = f2bf(acc[nt][r]);
  }
}

// ---------- agg1 + gemm2 fused; per-edge dinv[src] applied here ----------
__global__ __launch_bounds__(256) void k_agg1(const unsigned* __restrict__ xw1s2,
    const int* __restrict__ rowptr, const int* __restrict__ csr_src,
    const float* __restrict__ dinv, const float* __restrict__ b1,
    const float* __restrict__ w2, unsigned short* __restrict__ xw2s) {
  __shared__ float w2s[D_HID * N_CLS];
  for (int i = threadIdx.x; i < D_HID * N_CLS; i += 256) w2s[i] = w2[i];
  __syncthreads();
  int wave = threadIdx.x >> 6;
  int lane = threadIdx.x & 63;
  int h = lane >> 5, l = lane & 31;
  int node = blockIdx.x * 4 + wave;
  float dd = dinv[node];
  int beg = rowptr[node], end = rowptr[node + 1];
  float cx[8], cy[8];
#pragma unroll
  for (int j = 0; j < 8; j++) { cx[j] = 0.f; cy[j] = 0.f; }
  for (int e = beg + h; e < end; e += 16) {
    int idx[8]; bool val[8];
#pragma unroll
    for (int j = 0; j < 8; j++) {
      int ee = e + 2 * j;
      val[j] = ee < end;
      idx[j] = csr_src[val[j] ? ee : beg];
    }
    float dv[8];
#pragma unroll
    for (int j = 0; j < 8; j++) dv[j] = dinv[idx[j]];
#pragma unroll
    for (int j = 0; j < 8; j++) {
      float2 v = bf2f2(xw1s2[(size_t)idx[j] * 32 + l]);
      float w = val[j] ? dv[j] : 0.f;
      cx[j] += w * v.x;
      cy[j] += w * v.y;
    }
  }
  float sx = ((cx[0] + cx[1]) + (cx[2] + cx[3])) + ((cx[4] + cx[5]) + (cx[6] + cx[7]));
  float sy = ((cy[0] + cy[1]) + (cy[2] + cy[3])) + ((cy[4] + cy[5]) + (cy[6] + cy[7]));
  sx += __shfl_xor(sx, 32);
  sy += __shfl_xor(sy, 32);
  float2 self = bf2f2(xw1s2[(size_t)node * 32 + l]);
  float2 bb = ((const float2*)b1)[l];
  float vx = dd * (sx + dd * self.x) + bb.x;
  float vy = dd * (sy + dd * self.y) + bb.y;
  vx = vx > 0.f ? vx : 0.f;
  vy = vy > 0.f ? vy : 0.f;
  int c = lane & 31;
  float p = 0.f;
#pragma unroll
  for (int kk = 0; kk < 32; kk++) {
    int k = h * 32 + kk;
    float hv = (k & 1) ? __shfl(vy, k >> 1) : __shfl(vx, k >> 1);
    p += hv * w2s[k * N_CLS + c];
  }
  p += __shfl_xor(p, 32);
  if (lane < 32) xw2s[(size_t)node * N_CLS + c] = f2bf(p * dd);
}

// ---------- agg2 + log_softmax ----------
__global__ __launch_bounds__(256) void k_agg2(const unsigned* __restrict__ xw2s2,
    const int* __restrict__ rowptr, const int* __restrict__ csr_src,
    const float* __restrict__ dinv, const float* __restrict__ b2,
    float* __restrict__ out) {
  int wave = threadIdx.x >> 6;
  int lane = threadIdx.x & 63;
  int q = lane >> 4, l = lane & 15;
  int node = blockIdx.x * 4 + wave;
  float dd = dinv[node];
  int beg = rowptr[node], end = rowptr[node + 1];
  float cx[4], cy[4];
#pragma unroll
  for (int j = 0; j < 4; j++) { cx[j] = 0.f; cy[j] = 0.f; }
  for (int e = beg + q; e < end; e += 16) {
    int idx[4]; bool val[4];
#pragma unroll
    for (int j = 0; j < 4; j++) {
      int ee = e + 4 * j;
      val[j] = ee < end;
      idx[j] = csr_src[val[j] ? ee : beg];
    }
#pragma unroll
    for (int j = 0; j < 4; j++) {
      float2 v = bf2f2(xw2s2[(size_t)idx[j] * 16 + l]);
      cx[j] += val[j] ? v.x : 0.f;
      cy[j] += val[j] ? v.y : 0.f;
    }
  }
  float sx = (cx[0] + cx[1]) + (cx[2] + cx[3]);
  float sy = (cy[0] + cy[1]) + (cy[2] + cy[3]);
  sx += __shfl_xor(sx, 32); sy += __shfl_xor(sy, 32);
  sx += __shfl_xor(sx, 16); sy += __shfl_xor(sy, 16);
  float2 self = bf2f2(xw2s2[(size_t)node * 16 + l]);
  float2 bb = ((const float2*)b2)[l];
  float lx = dd * (sx + self.x) + bb.x;
  float ly = dd * (sy + self.y) + bb.y;
  float m = fmaxf(lx, ly);
#pragma unroll
  for (int o = 8; o > 0; o >>= 1) m = fmaxf(m, __shfl_xor(m, o));
  float s2 = __expf(lx - m) + __expf(ly - m);
#pragma unroll
  for (int o = 8; o > 0; o >>= 1) s2 += __shfl_xor(s2, o);
  float lse = m + __logf(s2);
  if (lane < 16)
    ((float2*)out)[(size_t)node * 16 + l] = make_float2(lx - lse, ly - lse);
}

extern "C" void kernel_launch(void* const* d_in, const int* in_sizes, int n_in,
                              void* d_out, int out_size, void* d_ws, size_t ws_size,
                              hipStream_t stream) {
  (void)n_in; (void)out_size; (void)ws_size;
  const float* x  = (const float*)d_in[0];
  const int*   ei = (const int*)d_in[1];
  const float* w1 = (const float*)d_in[2];
  const float* b1 = (const float*)d_in[3];
  const float* w2 = (const float*)d_in[4];
  const float* b2 = (const float*)d_in[5];
  float* out = (float*)d_out;
  int e = in_sizes[1] / 2;
  const int* src = ei;
  const int* dst = ei + e;

  char* ws = (char*)d_ws;
  int* H              = (int*)(ws + 0x0000000);           // 256KB (block-major)
  int* Hs             = (int*)(ws + 0x0040000);           // 256KB (bin-major, scanned)
  int* btot           = (int*)(ws + 0x0080000);           // 1KB
  int* btoff          = (int*)(ws + 0x0080400);           // 1KB
  int* rowptr         = (int*)(ws + 0x0081000);           // 256KB + 4
  float* dinv         = (float*)(ws + 0x00D0000);         // 256KB
  unsigned* pk        = (unsigned*)(ws + 0x0200000);      // 4MB (bucket-sorted packed edges)
  int* csr_src        = (int*)(ws + 0x0600000);           // 4MB
  unsigned short* w1t = (unsigned short*)(ws + 0x0A00000);// 128KB
  unsigned short* xw1s= (unsigned short*)(ws + 0x0A20000);// 8MB (bf16, UNSCALED)
  unsigned short* xw2s= (unsigned short*)(ws + 0x1220000);// 4MB (bf16)

  int e4 = e / 4;
  k_hist_w1t  <<<NSB + 256, 256, 0, stream>>>(dst, H, w1, w1t, e4);
  k_scan_bin  <<<NBUK, 256, 0, stream>>>(H, Hs, btot);
  k_scan_tot  <<<1, 256, 0, stream>>>(btot, btoff, rowptr, e);
  k_scatter   <<<NSB, 256, 0, stream>>>(dst, src, Hs, btoff, pk, e4);
  k_bucket_csr<<<NBUK, 256, 0, stream>>>(pk, btoff, btot, rowptr, csr_src, dinv);
  k_gemm1     <<<2048, 256, 0, stream>>>(x, w1t, xw1s);  // doubled for measurement
  k_agg1      <<<N_NODES / 4, 256, 0, stream>>>((const unsigned*)xw1s, rowptr, csr_src,
                                                dinv, b1, w2, xw2s);
  k_agg2      <<<N_NODES / 4, 256, 0, stream>>>((const unsigned*)xw2s, rowptr, csr_src,
                                                dinv, b2, out);
}

// Round 8
// 513.469 us; speedup vs baseline: 1.8308x; 1.1692x over previous
//
#include <hip/hip_runtime.h>
#include <hip/hip_bf16.h>

#define N_NODES 65536
#define D_IN 1024
#define D_HID 64
#define N_CLS 32
#define NBUK 256   // buckets keyed by dst >> 8
#define NSB 256    // scatter/hist blocks (4096 edges each)

typedef short short8 __attribute__((ext_vector_type(8)));
typedef float floatx4 __attribute__((ext_vector_type(4)));

// ---------- helpers ----------
__device__ __forceinline__ unsigned short f2bf(float f) {
  union { float f; unsigned u; } cv; cv.f = f;
  unsigned r = (cv.u + 0x7FFFu + ((cv.u >> 16) & 1u)) >> 16;
  return (unsigned short)r;
}
__device__ __forceinline__ float2 bf2f2(unsigned v) {
  union { unsigned u; float f; } a, b;
  a.u = v << 16;
  b.u = v & 0xFFFF0000u;
  return make_float2(a.f, b.f);  // (elem 2l, elem 2l+1)
}

// ---------- pass 1: histogram by dst>>8 (blocks 0..255) + W1^T (blocks 256..319)
//            1024 threads: 16 waves/CU for latency hiding ----------
__global__ __launch_bounds__(1024) void k_hist_w1t(
    const int* __restrict__ dst, int* __restrict__ H,
    const float* __restrict__ w1, unsigned short* __restrict__ w1t, int e4) {
  int b = blockIdx.x, t = threadIdx.x;
  if (b >= NSB) {
    int i = (b - NSB) * 1024 + t;  // [0, 65536)
    int k = i / D_HID, n = i % D_HID;
    w1t[n * D_IN + k] = f2bf(w1[i]);
    return;
  }
  __shared__ int hist[NBUK];
  if (t < NBUK) hist[t] = 0;
  __syncthreads();
  int i4 = b * 1024 + t;  // one int4 (4 edges) per thread
  if (i4 < e4) {
    int4 d = ((const int4*)dst)[i4];
    atomicAdd(&hist[d.x >> 8], 1);
    atomicAdd(&hist[d.y >> 8], 1);
    atomicAdd(&hist[d.z >> 8], 1);
    atomicAdd(&hist[d.w >> 8], 1);
  }
  __syncthreads();
  if (t < NBUK) H[b * NBUK + t] = hist[t];  // block-major: coalesced
}

// ---------- pass 2a: per-bin exclusive scan over 256 blocks -> Hs (bin-major) ----------
__global__ void k_scan_bin(const int* __restrict__ H, int* __restrict__ Hs,
                           int* __restrict__ btot) {
  int bin = blockIdx.x, t = threadIdx.x;
  int v = H[t * NBUK + bin];
  __shared__ int s[256];
  s[t] = v;
  __syncthreads();
  for (int off = 1; off < 256; off <<= 1) {
    int x = (t >= off) ? s[t - off] : 0;
    __syncthreads();
    s[t] += x;
    __syncthreads();
  }
  Hs[bin * NSB + t] = s[t] - v;
  if (t == 255) btot[bin] = s[255];
}

// ---------- pass 2b: scan bucket totals -> bucket base offsets ----------
__global__ void k_scan_tot(const int* __restrict__ btot, int* __restrict__ btoff,
                           int* __restrict__ rowptr, int e) {
  __shared__ int s[256];
  int t = threadIdx.x;
  int v = btot[t];
  s[t] = v;
  __syncthreads();
  for (int off = 1; off < 256; off <<= 1) {
    int x = (t >= off) ? s[t - off] : 0;
    __syncthreads();
    s[t] += x;
    __syncthreads();
  }
  btoff[t] = s[t] - v;
  if (t == 0) rowptr[N_NODES] = e;
}

// ---------- pass 3: LDS-staged bucket scatter; 1024 threads ----------
__global__ __launch_bounds__(1024) void k_scatter(
    const int* __restrict__ dst, const int* __restrict__ src,
    const int* __restrict__ Hs, const int* __restrict__ btoff,
    unsigned* __restrict__ pk, int e4) {
  __shared__ int cnt[NBUK], sc[NBUK], cur[NBUK], base2[NBUK];
  __shared__ unsigned stage[4096];
  int b = blockIdx.x, t = threadIdx.x;
  if (t < NBUK) cnt[t] = 0;
  __syncthreads();
  int i4 = b * 1024 + t;  // one int4 per thread
  bool ok = i4 < e4;
  int4 dv, sv;
  if (ok) {
    dv = ((const int4*)dst)[i4];
    sv = ((const int4*)src)[i4];
    atomicAdd(&cnt[dv.x >> 8], 1);
    atomicAdd(&cnt[dv.y >> 8], 1);
    atomicAdd(&cnt[dv.z >> 8], 1);
    atomicAdd(&cnt[dv.w >> 8], 1);
  }
  __syncthreads();
  int c = (t < NBUK) ? cnt[t] : 0;
  if (t < NBUK) sc[t] = c;
  __syncthreads();
  for (int off = 1; off < 256; off <<= 1) {
    int xv = (t < NBUK && t >= off) ? sc[t - off] : 0;
    __syncthreads();
    if (t < NBUK) sc[t] += xv;
    __syncthreads();
  }
  if (t < NBUK) {
    int excl = sc[t] - c;
    cur[t] = excl;
    base2[t] = btoff[t] + Hs[t * NSB + b] - excl;  // pk dest = base2[bin] + stagedIdx
  }
  __syncthreads();
  int tot = sc[255];
  if (ok) {
    int d[4] = {dv.x, dv.y, dv.z, dv.w};
    int s[4] = {sv.x, sv.y, sv.z, sv.w};
#pragma unroll
    for (int j = 0; j < 4; j++) {
      int pos = atomicAdd(&cur[d[j] >> 8], 1);
      stage[pos] = ((unsigned)d[j] << 16) | (unsigned)s[j];
    }
  }
  __syncthreads();
  for (int i = t; i < tot; i += 1024) {
    unsigned u = stage[i];
    pk[base2[u >> 24] + i] = u;
  }
}

// ---------- pass 4: per-bucket local CSR; 1024 threads ----------
__global__ __launch_bounds__(1024) void k_bucket_csr(
    const unsigned* __restrict__ pk, const int* __restrict__ btoff,
    const int* __restrict__ btot, int* __restrict__ rowptr,
    int* __restrict__ csr_src, float* __restrict__ dinv) {
  __shared__ int cnt[NBUK], sc[NBUK], cur[NBUK];
  int bin = blockIdx.x, t = threadIdx.x;
  if (t < NBUK) cnt[t] = 0;
  __syncthreads();
  int beg = btoff[bin], len = btot[bin];
  for (int i = t; i < len; i += 1024)
    atomicAdd(&cnt[(pk[beg + i] >> 16) & 255], 1);
  __syncthreads();
  int c = (t < NBUK) ? cnt[t] : 0;
  if (t < NBUK) sc[t] = c;
  __syncthreads();
  for (int off = 1; off < 256; off <<= 1) {
    int x = (t < NBUK && t >= off) ? sc[t - off] : 0;
    __syncthreads();
    if (t < NBUK) sc[t] += x;
    __syncthreads();
  }
  if (t < NBUK) {
    int excl = sc[t] - c;
    int node = bin * 256 + t;
    rowptr[node] = beg + excl;
    dinv[node] = rsqrtf((float)(c + 1));
    cur[t] = excl;
  }
  __syncthreads();
  for (int i = t; i < len; i += 1024) {
    unsigned u = pk[beg + i];
    int p = atomicAdd(&cur[(u >> 16) & 255], 1);
    csr_src[beg + p] = (int)(u & 0xFFFFu);
  }
}

// ---------- GEMM1: xw1 = x @ W1 (UNSCALED), bf16 out; depth-4 A prefetch ----------
// Consume chunk at KC from PA, prefetch chunk KC+256 into PA (4 chunks in flight).
#define GCHUNK(PA, KC) do {                                                    \
    float4 c0 = PA[0], c1 = PA[1], c2 = PA[2], c3 = PA[3];                     \
    if ((KC) + 256 < D_IN) {                                                   \
      PA[0] = *(const float4*)(xrow + (KC) + 256);                             \
      PA[1] = *(const float4*)(xrow + (KC) + 260);                             \
      PA[2] = *(const float4*)(xrow + (KC) + 288);                             \
      PA[3] = *(const float4*)(xrow + (KC) + 292);                             \
    }                                                                          \
    int kb = ((KC) + 64 < D_IN) ? (KC) + 64 : (KC);                            \
    float av0[8] = {c0.x, c0.y, c0.z, c0.w, c1.x, c1.y, c1.z, c1.w};           \
    float av1[8] = {c2.x, c2.y, c2.z, c2.w, c3.x, c3.y, c3.z, c3.w};           \
    short8 af0, af1;                                                           \
    unsigned* u0 = (unsigned*)&af0;                                            \
    unsigned* u1 = (unsigned*)&af1;                                            \
    _Pragma("unroll") for (int j = 0; j < 4; j++) {                            \
      asm("v_cvt_pk_bf16_f32 %0, %1, %2"                                       \
          : "=v"(u0[j]) : "v"(av0[2 * j]), "v"(av0[2 * j + 1]));               \
      asm("v_cvt_pk_bf16_f32 %0, %1, %2"                                       \
          : "=v"(u1[j]) : "v"(av1[2 * j]), "v"(av1[2 * j + 1]));               \
    }                                                                          \
    _Pragma("unroll") for (int nt = 0; nt < 4; nt++)                           \
      acc[nt] = __builtin_amdgcn_mfma_f32_16x16x32_bf16(af0, bf0[nt], acc[nt], 0, 0, 0); \
    _Pragma("unroll") for (int nt = 0; nt < 4; nt++)                           \
      bf0[nt] = *(const short8*)(bbase + (size_t)(nt * 16 + l16) * D_IN + kb); \
    _Pragma("unroll") for (int nt = 0; nt < 4; nt++)                           \
      acc[nt] = __builtin_amdgcn_mfma_f32_16x16x32_bf16(af1, bf1[nt], acc[nt], 0, 0, 0); \
    _Pragma("unroll") for (int nt = 0; nt < 4; nt++)                           \
      bf1[nt] = *(const short8*)(bbase + (size_t)(nt * 16 + l16) * D_IN + kb + 32); \
  } while (0)

__global__ __launch_bounds__(256) void k_gemm1(
    const float* __restrict__ x, const unsigned short* __restrict__ w1t,
    unsigned short* __restrict__ xw1s) {
  int wave = threadIdx.x >> 6;
  int lane = threadIdx.x & 63;
  int quad = lane >> 4;
  int l16 = lane & 15;
  int rowbase = blockIdx.x * 64 + wave * 16;
  const float* xrow = x + (size_t)(rowbase + l16) * D_IN + quad * 8;
  const unsigned short* bbase = w1t + quad * 8;
  floatx4 acc[4];
#pragma unroll
  for (int nt = 0; nt < 4; nt++) acc[nt] = (floatx4){0.f, 0.f, 0.f, 0.f};
  // prologue: 4 A-chunks in flight (16 loads), chunk-0 B fragments
  float4 pa0[4], pa1[4], pa2[4], pa3[4];
#pragma unroll
  for (int cc = 0; cc < 4; cc++) {
    float4* pp = (cc == 0) ? pa0 : (cc == 1) ? pa1 : (cc == 2) ? pa2 : pa3;
    pp[0] = *(const float4*)(xrow + cc * 64 + 0);
    pp[1] = *(const float4*)(xrow + cc * 64 + 4);
    pp[2] = *(const float4*)(xrow + cc * 64 + 32);
    pp[3] = *(const float4*)(xrow + cc * 64 + 36);
  }
  short8 bf0[4], bf1[4];
#pragma unroll
  for (int nt = 0; nt < 4; nt++) {
    const unsigned short* bp = bbase + (size_t)(nt * 16 + l16) * D_IN;
    bf0[nt] = *(const short8*)(bp);
    bf1[nt] = *(const short8*)(bp + 32);
  }
#pragma unroll
  for (int k0 = 0; k0 < D_IN; k0 += 256) {
    GCHUNK(pa0, k0);
    GCHUNK(pa1, k0 + 64);
    GCHUNK(pa2, k0 + 128);
    GCHUNK(pa3, k0 + 192);
  }
#pragma unroll
  for (int r = 0; r < 4; r++) {
    int row = rowbase + quad * 4 + r;
#pragma unroll
    for (int nt = 0; nt < 4; nt++)
      xw1s[(size_t)row * D_HID + nt * 16 + l16] = f2bf(acc[nt][r]);
  }
}

// ---------- agg1 + gemm2 fused; per-edge dinv[src] applied here ----------
__global__ __launch_bounds__(256) void k_agg1(const unsigned* __restrict__ xw1s2,
    const int* __restrict__ rowptr, const int* __restrict__ csr_src,
    const float* __restrict__ dinv, const float* __restrict__ b1,
    const float* __restrict__ w2, unsigned short* __restrict__ xw2s) {
  __shared__ float w2s[D_HID * N_CLS];
  for (int i = threadIdx.x; i < D_HID * N_CLS; i += 256) w2s[i] = w2[i];
  __syncthreads();
  int wave = threadIdx.x >> 6;
  int lane = threadIdx.x & 63;
  int h = lane >> 5, l = lane & 31;
  int node = blockIdx.x * 4 + wave;
  float dd = dinv[node];
  int beg = rowptr[node], end = rowptr[node + 1];
  float cx[8], cy[8];
#pragma unroll
  for (int j = 0; j < 8; j++) { cx[j] = 0.f; cy[j] = 0.f; }
  for (int e = beg + h; e < end; e += 16) {
    int idx[8]; bool val[8];
#pragma unroll
    for (int j = 0; j < 8; j++) {
      int ee = e + 2 * j;
      val[j] = ee < end;
      idx[j] = csr_src[val[j] ? ee : beg];
    }
    float dv[8];
#pragma unroll
    for (int j = 0; j < 8; j++) dv[j] = dinv[idx[j]];
#pragma unroll
    for (int j = 0; j < 8; j++) {
      float2 v = bf2f2(xw1s2[(size_t)idx[j] * 32 + l]);
      float w = val[j] ? dv[j] : 0.f;
      cx[j] += w * v.x;
      cy[j] += w * v.y;
    }
  }
  float sx = ((cx[0] + cx[1]) + (cx[2] + cx[3])) + ((cx[4] + cx[5]) + (cx[6] + cx[7]));
  float sy = ((cy[0] + cy[1]) + (cy[2] + cy[3])) + ((cy[4] + cy[5]) + (cy[6] + cy[7]));
  sx += __shfl_xor(sx, 32);
  sy += __shfl_xor(sy, 32);
  float2 self = bf2f2(xw1s2[(size_t)node * 32 + l]);
  float2 bb = ((const float2*)b1)[l];
  float vx = dd * (sx + dd * self.x) + bb.x;
  float vy = dd * (sy + dd * self.y) + bb.y;
  vx = vx > 0.f ? vx : 0.f;
  vy = vy > 0.f ? vy : 0.f;
  int c = lane & 31;
  float p = 0.f;
#pragma unroll
  for (int kk = 0; kk < 32; kk++) {
    int k = h * 32 + kk;
    float hv = (k & 1) ? __shfl(vy, k >> 1) : __shfl(vx, k >> 1);
    p += hv * w2s[k * N_CLS + c];
  }
  p += __shfl_xor(p, 32);
  if (lane < 32) xw2s[(size_t)node * N_CLS + c] = f2bf(p * dd);
}

// ---------- agg2 + log_softmax ----------
__global__ __launch_bounds__(256) void k_agg2(const unsigned* __restrict__ xw2s2,
    const int* __restrict__ rowptr, const int* __restrict__ csr_src,
    const float* __restrict__ dinv, const float* __restrict__ b2,
    float* __restrict__ out) {
  int wave = threadIdx.x >> 6;
  int lane = threadIdx.x & 63;
  int q = lane >> 4, l = lane & 15;
  int node = blockIdx.x * 4 + wave;
  float dd = dinv[node];
  int beg = rowptr[node], end = rowptr[node + 1];
  float cx[4], cy[4];
#pragma unroll
  for (int j = 0; j < 4; j++) { cx[j] = 0.f; cy[j] = 0.f; }
  for (int e = beg + q; e < end; e += 16) {
    int idx[4]; bool val[4];
#pragma unroll
    for (int j = 0; j < 4; j++) {
      int ee = e + 4 * j;
      val[j] = ee < end;
      idx[j] = csr_src[val[j] ? ee : beg];
    }
#pragma unroll
    for (int j = 0; j < 4; j++) {
      float2 v = bf2f2(xw2s2[(size_t)idx[j] * 16 + l]);
      cx[j] += val[j] ? v.x : 0.f;
      cy[j] += val[j] ? v.y : 0.f;
    }
  }
  float sx = (cx[0] + cx[1]) + (cx[2] + cx[3]);
  float sy = (cy[0] + cy[1]) + (cy[2] + cy[3]);
  sx += __shfl_xor(sx, 32); sy += __shfl_xor(sy, 32);
  sx += __shfl_xor(sx, 16); sy += __shfl_xor(sy, 16);
  float2 self = bf2f2(xw2s2[(size_t)node * 16 + l]);
  float2 bb = ((const float2*)b2)[l];
  float lx = dd * (sx + self.x) + bb.x;
  float ly = dd * (sy + self.y) + bb.y;
  float m = fmaxf(lx, ly);
#pragma unroll
  for (int o = 8; o > 0; o >>= 1) m = fmaxf(m, __shfl_xor(m, o));
  float s2 = __expf(lx - m) + __expf(ly - m);
#pragma unroll
  for (int o = 8; o > 0; o >>= 1) s2 += __shfl_xor(s2, o);
  float lse = m + __logf(s2);
  if (lane < 16)
    ((float2*)out)[(size_t)node * 16 + l] = make_float2(lx - lse, ly - lse);
}

extern "C" void kernel_launch(void* const* d_in, const int* in_sizes, int n_in,
                              void* d_out, int out_size, void* d_ws, size_t ws_size,
                              hipStream_t stream) {
  (void)n_in; (void)out_size; (void)ws_size;
  const float* x  = (const float*)d_in[0];
  const int*   ei = (const int*)d_in[1];
  const float* w1 = (const float*)d_in[2];
  const float* b1 = (const float*)d_in[3];
  const float* w2 = (const float*)d_in[4];
  const float* b2 = (const float*)d_in[5];
  float* out = (float*)d_out;
  int e = in_sizes[1] / 2;
  const int* src = ei;
  const int* dst = ei + e;

  char* ws = (char*)d_ws;
  int* H              = (int*)(ws + 0x0000000);           // 256KB (block-major)
  int* Hs             = (int*)(ws + 0x0040000);           // 256KB (bin-major, scanned)
  int* btot           = (int*)(ws + 0x0080000);           // 1KB
  int* btoff          = (int*)(ws + 0x0080400);           // 1KB
  int* rowptr         = (int*)(ws + 0x0081000);           // 256KB + 4
  float* dinv         = (float*)(ws + 0x00D0000);         // 256KB
  unsigned* pk        = (unsigned*)(ws + 0x0200000);      // 4MB (bucket-sorted packed edges)
  int* csr_src        = (int*)(ws + 0x0600000);           // 4MB
  unsigned short* w1t = (unsigned short*)(ws + 0x0A00000);// 128KB
  unsigned short* xw1s= (unsigned short*)(ws + 0x0A20000);// 8MB (bf16, UNSCALED)
  unsigned short* xw2s= (unsigned short*)(ws + 0x1220000);// 4MB (bf16)

  int e4 = e / 4;
  k_hist_w1t  <<<NSB + 64, 1024, 0, stream>>>(dst, H, w1, w1t, e4);
  k_scan_bin  <<<NBUK, 256, 0, stream>>>(H, Hs, btot);
  k_scan_tot  <<<1, 256, 0, stream>>>(btot, btoff, rowptr, e);
  k_scatter   <<<NSB, 1024, 0, stream>>>(dst, src, Hs, btoff, pk, e4);
  k_bucket_csr<<<NBUK, 1024, 0, stream>>>(pk, btoff, btot, rowptr, csr_src, dinv);
  k_gemm1     <<<N_NODES / 64, 256, 0, stream>>>(x, w1t, xw1s);
  k_agg1      <<<N_NODES / 4, 256, 0, stream>>>((const unsigned*)xw1s, rowptr, csr_src,
                                                dinv, b1, w2, xw2s);
  k_agg2      <<<N_NODES / 4, 256, 0, stream>>>((const unsigned*)xw2s, rowptr, csr_src,
                                                dinv, b2, out);
}

// Round 9
// 508.390 us; speedup vs baseline: 1.8491x; 1.0100x over previous
//
#include <hip/hip_runtime.h>
#include <hip/hip_bf16.h>

#define N_NODES 65536
#define D_IN 1024
#define D_HID 64
#define N_CLS 32
#define NBUK 256   // buckets keyed by dst >> 8
#define NSB 256    // scatter/hist blocks (4096 edges each)

typedef short short8 __attribute__((ext_vector_type(8)));
typedef float floatx4 __attribute__((ext_vector_type(4)));

// ---------- helpers ----------
__device__ __forceinline__ unsigned short f2bf(float f) {
  union { float f; unsigned u; } cv; cv.f = f;
  unsigned r = (cv.u + 0x7FFFu + ((cv.u >> 16) & 1u)) >> 16;
  return (unsigned short)r;
}
__device__ __forceinline__ float2 bf2f2(unsigned v) {
  union { unsigned u; float f; } a, b;
  a.u = v << 16;
  b.u = v & 0xFFFF0000u;
  return make_float2(a.f, b.f);  // (elem 2l, elem 2l+1)
}

// ---------- pass 1: histogram by dst>>8 (blocks 0..255, H block-major)
//            + W1^T -> bf16 (blocks 256..511) ----------
__global__ void k_hist_w1t(const int* __restrict__ dst, int* __restrict__ H,
                           const float* __restrict__ w1, unsigned short* __restrict__ w1t,
                           int e4) {
  int b = blockIdx.x, t = threadIdx.x;
  if (b >= NSB) {
    int i = (b - NSB) * 256 + t;  // [0, 65536)
    int k = i / D_HID, n = i % D_HID;
    w1t[n * D_IN + k] = f2bf(w1[i]);
    return;
  }
  __shared__ int hist[NBUK];
  hist[t] = 0;
  __syncthreads();
  const int4* d4 = (const int4*)dst + b * 1024;
#pragma unroll
  for (int p = 0; p < 4; p++) {
    int i4 = b * 1024 + p * 256 + t;
    if (i4 < e4) {
      int4 d = d4[p * 256 + t];
      atomicAdd(&hist[d.x >> 8], 1);
      atomicAdd(&hist[d.y >> 8], 1);
      atomicAdd(&hist[d.z >> 8], 1);
      atomicAdd(&hist[d.w >> 8], 1);
    }
  }
  __syncthreads();
  H[b * NBUK + t] = hist[t];  // block-major: coalesced
}

// ---------- pass 2a: per-bin exclusive scan over 256 blocks -> Hs (bin-major) ----------
__global__ void k_scan_bin(const int* __restrict__ H, int* __restrict__ Hs,
                           int* __restrict__ btot) {
  int bin = blockIdx.x, t = threadIdx.x;
  int v = H[t * NBUK + bin];
  __shared__ int s[256];
  s[t] = v;
  __syncthreads();
  for (int off = 1; off < 256; off <<= 1) {
    int x = (t >= off) ? s[t - off] : 0;
    __syncthreads();
    s[t] += x;
    __syncthreads();
  }
  Hs[bin * NSB + t] = s[t] - v;
  if (t == 255) btot[bin] = s[255];
}

// ---------- pass 2b: scan bucket totals -> bucket base offsets ----------
__global__ void k_scan_tot(const int* __restrict__ btot, int* __restrict__ btoff,
                           int* __restrict__ rowptr, int e) {
  __shared__ int s[256];
  int t = threadIdx.x;
  int v = btot[t];
  s[t] = v;
  __syncthreads();
  for (int off = 1; off < 256; off <<= 1) {
    int x = (t >= off) ? s[t - off] : 0;
    __syncthreads();
    s[t] += x;
    __syncthreads();
  }
  btoff[t] = s[t] - v;
  if (t == 0) rowptr[N_NODES] = e;
}

// ---------- pass 3: LDS-staged bucket scatter (256 blocks, 256 threads) ----------
__global__ __launch_bounds__(256) void k_scatter(
    const int* __restrict__ dst, const int* __restrict__ src,
    const int* __restrict__ Hs, const int* __restrict__ btoff,
    unsigned* __restrict__ pk, int e4) {
  __shared__ int cnt[NBUK], sc[NBUK], cur[NBUK], base2[NBUK];
  __shared__ unsigned stage[4096];
  int b = blockIdx.x, t = threadIdx.x;
  cnt[t] = 0;
  __syncthreads();
  const int4* d4 = (const int4*)dst + b * 1024;
  const int4* s4 = (const int4*)src + b * 1024;
  int4 dv[4], sv[4]; bool ok[4];
#pragma unroll
  for (int p = 0; p < 4; p++) {
    int i4 = b * 1024 + p * 256 + t;
    ok[p] = i4 < e4;
    if (ok[p]) {
      dv[p] = d4[p * 256 + t];
      sv[p] = s4[p * 256 + t];
      atomicAdd(&cnt[dv[p].x >> 8], 1);
      atomicAdd(&cnt[dv[p].y >> 8], 1);
      atomicAdd(&cnt[dv[p].z >> 8], 1);
      atomicAdd(&cnt[dv[p].w >> 8], 1);
    }
  }
  __syncthreads();
  int c = cnt[t];
  sc[t] = c;
  __syncthreads();
  for (int off = 1; off < 256; off <<= 1) {
    int xv = (t >= off) ? sc[t - off] : 0;
    __syncthreads();
    sc[t] += xv;
    __syncthreads();
  }
  int excl = sc[t] - c;
  cur[t] = excl;
  base2[t] = btoff[t] + Hs[t * NSB + b] - excl;  // pk dest = base2[bin] + stagedIdx
  __syncthreads();
  int tot = sc[255];
#pragma unroll
  for (int p = 0; p < 4; p++) {
    if (ok[p]) {
      int d[4] = {dv[p].x, dv[p].y, dv[p].z, dv[p].w};
      int s[4] = {sv[p].x, sv[p].y, sv[p].z, sv[p].w};
#pragma unroll
      for (int j = 0; j < 4; j++) {
        int pos = atomicAdd(&cur[d[j] >> 8], 1);
        stage[pos] = ((unsigned)d[j] << 16) | (unsigned)s[j];
      }
    }
  }
  __syncthreads();
  for (int i = t; i < tot; i += 256) {
    unsigned u = stage[i];
    pk[base2[u >> 24] + i] = u;
  }
}

// ---------- pass 4: per-bucket local CSR (rowptr, dinv, csr_src) ----------
__global__ void k_bucket_csr(const unsigned* __restrict__ pk, const int* __restrict__ btoff,
                             const int* __restrict__ btot, int* __restrict__ rowptr,
                             int* __restrict__ csr_src, float* __restrict__ dinv) {
  __shared__ int cnt[NBUK], sc[NBUK], cur[NBUK];
  int bin = blockIdx.x, t = threadIdx.x;
  cnt[t] = 0;
  __syncthreads();
  int beg = btoff[bin], len = btot[bin];
  for (int i = t; i < len; i += 256)
    atomicAdd(&cnt[(pk[beg + i] >> 16) & 255], 1);
  __syncthreads();
  int c = cnt[t];
  sc[t] = c;
  __syncthreads();
  for (int off = 1; off < 256; off <<= 1) {
    int x = (t >= off) ? sc[t - off] : 0;
    __syncthreads();
    sc[t] += x;
    __syncthreads();
  }
  int excl = sc[t] - c;
  int node = bin * 256 + t;
  rowptr[node] = beg + excl;
  dinv[node] = rsqrtf((float)(c + 1));
  cur[t] = excl;
  __syncthreads();
  for (int i = t; i < len; i += 256) {
    unsigned u = pk[beg + i];
    int p = atomicAdd(&cur[(u >> 16) & 255], 1);
    csr_src[beg + p] = (int)(u & 0xFFFFu);
  }
}

// ---------- GEMM1, K-split 2-way: 2048 blocks x 256 = 32 waves/CU ----------
// Block covers 32 rows; waves (rowgrp=wave&1, kh=wave>>1) each do 512 of K with
// the proven depth-2 prefetch; kh=1 partials combine via 8KB LDS + one barrier.
#define GCHUNK(PA, KC) do {                                                    \
    float4 c0 = PA[0], c1 = PA[1], c2 = PA[2], c3 = PA[3];                     \
    if ((KC) + 128 < 512) {                                                    \
      PA[0] = *(const float4*)(xrow + (KC) + 128);                             \
      PA[1] = *(const float4*)(xrow + (KC) + 132);                             \
      PA[2] = *(const float4*)(xrow + (KC) + 160);                             \
      PA[3] = *(const float4*)(xrow + (KC) + 164);                             \
    }                                                                          \
    int kb = ((KC) + 64 < 512) ? (KC) + 64 : (KC);                             \
    float av0[8] = {c0.x, c0.y, c0.z, c0.w, c1.x, c1.y, c1.z, c1.w};           \
    float av1[8] = {c2.x, c2.y, c2.z, c2.w, c3.x, c3.y, c3.z, c3.w};           \
    short8 af0, af1;                                                           \
    unsigned* u0 = (unsigned*)&af0;                                            \
    unsigned* u1 = (unsigned*)&af1;                                            \
    _Pragma("unroll") for (int j = 0; j < 4; j++) {                            \
      asm("v_cvt_pk_bf16_f32 %0, %1, %2"                                       \
          : "=v"(u0[j]) : "v"(av0[2 * j]), "v"(av0[2 * j + 1]));               \
      asm("v_cvt_pk_bf16_f32 %0, %1, %2"                                       \
          : "=v"(u1[j]) : "v"(av1[2 * j]), "v"(av1[2 * j + 1]));               \
    }                                                                          \
    _Pragma("unroll") for (int nt = 0; nt < 4; nt++)                           \
      acc[nt] = __builtin_amdgcn_mfma_f32_16x16x32_bf16(af0, bf0[nt], acc[nt], 0, 0, 0); \
    _Pragma("unroll") for (int nt = 0; nt < 4; nt++)                           \
      bf0[nt] = *(const short8*)(bbase + (size_t)(nt * 16 + l16) * D_IN + kb); \
    _Pragma("unroll") for (int nt = 0; nt < 4; nt++)                           \
      acc[nt] = __builtin_amdgcn_mfma_f32_16x16x32_bf16(af1, bf1[nt], acc[nt], 0, 0, 0); \
    _Pragma("unroll") for (int nt = 0; nt < 4; nt++)                           \
      bf1[nt] = *(const short8*)(bbase + (size_t)(nt * 16 + l16) * D_IN + kb + 32); \
  } while (0)

__global__ __launch_bounds__(256) void k_gemm1(
    const float* __restrict__ x, const unsigned short* __restrict__ w1t,
    unsigned short* __restrict__ xw1s) {
  __shared__ float red[2][16][64];  // 8KB: kh=1 partial sums
  int wave = threadIdx.x >> 6;
  int lane = threadIdx.x & 63;
  int quad = lane >> 4;
  int l16 = lane & 15;
  int rowgrp = wave & 1;
  int kh = wave >> 1;
  int rowbase = blockIdx.x * 32 + rowgrp * 16;
  int kbeg = kh * 512;
  const float* xrow = x + (size_t)(rowbase + l16) * D_IN + kbeg + quad * 8;
  const unsigned short* bbase = w1t + kbeg + quad * 8;
  floatx4 acc[4];
#pragma unroll
  for (int nt = 0; nt < 4; nt++) acc[nt] = (floatx4){0.f, 0.f, 0.f, 0.f};
  // depth-2 A prefetch + chunk-0 B fragments
  float4 pa0[4], pa1[4];
  pa0[0] = *(const float4*)(xrow + 0);
  pa0[1] = *(const float4*)(xrow + 4);
  pa0[2] = *(const float4*)(xrow + 32);
  pa0[3] = *(const float4*)(xrow + 36);
  pa1[0] = *(const float4*)(xrow + 64);
  pa1[1] = *(const float4*)(xrow + 68);
  pa1[2] = *(const float4*)(xrow + 96);
  pa1[3] = *(const float4*)(xrow + 100);
  short8 bf0[4], bf1[4];
#pragma unroll
  for (int nt = 0; nt < 4; nt++) {
    const unsigned short* bp = bbase + (size_t)(nt * 16 + l16) * D_IN;
    bf0[nt] = *(const short8*)(bp);
    bf1[nt] = *(const short8*)(bp + 32);
  }
#pragma unroll
  for (int k0 = 0; k0 < 512; k0 += 128) {
    GCHUNK(pa0, k0);
    GCHUNK(pa1, k0 + 64);
  }
  if (kh == 1) {
#pragma unroll
    for (int nt = 0; nt < 4; nt++)
#pragma unroll
      for (int r = 0; r < 4; r++)
        red[rowgrp][quad * 4 + r][nt * 16 + l16] = acc[nt][r];
  }
  __syncthreads();
  if (kh == 0) {
#pragma unroll
    for (int r = 0; r < 4; r++) {
      int row = rowbase + quad * 4 + r;
#pragma unroll
      for (int nt = 0; nt < 4; nt++) {
        float v = acc[nt][r] + red[rowgrp][quad * 4 + r][nt * 16 + l16];
        xw1s[(size_t)row * D_HID + nt * 16 + l16] = f2bf(v);
      }
    }
  }
}

// ---------- agg1 + gemm2 fused; per-edge dinv[src] applied here ----------
__global__ __launch_bounds__(256) void k_agg1(const unsigned* __restrict__ xw1s2,
    const int* __restrict__ rowptr, const int* __restrict__ csr_src,
    const float* __restrict__ dinv, const float* __restrict__ b1,
    const float* __restrict__ w2, unsigned short* __restrict__ xw2s) {
  __shared__ float w2s[D_HID * N_CLS];
  for (int i = threadIdx.x; i < D_HID * N_CLS; i += 256) w2s[i] = w2[i];
  __syncthreads();
  int wave = threadIdx.x >> 6;
  int lane = threadIdx.x & 63;
  int h = lane >> 5, l = lane & 31;
  int node = blockIdx.x * 4 + wave;
  float dd = dinv[node];
  int beg = rowptr[node], end = rowptr[node + 1];
  float cx[8], cy[8];
#pragma unroll
  for (int j = 0; j < 8; j++) { cx[j] = 0.f; cy[j] = 0.f; }
  for (int e = beg + h; e < end; e += 16) {
    int idx[8]; bool val[8];
#pragma unroll
    for (int j = 0; j < 8; j++) {
      int ee = e + 2 * j;
      val[j] = ee < end;
      idx[j] = csr_src[val[j] ? ee : beg];
    }
    float dv[8];
#pragma unroll
    for (int j = 0; j < 8; j++) dv[j] = dinv[idx[j]];
#pragma unroll
    for (int j = 0; j < 8; j++) {
      float2 v = bf2f2(xw1s2[(size_t)idx[j] * 32 + l]);
      float w = val[j] ? dv[j] : 0.f;
      cx[j] += w * v.x;
      cy[j] += w * v.y;
    }
  }
  float sx = ((cx[0] + cx[1]) + (cx[2] + cx[3])) + ((cx[4] + cx[5]) + (cx[6] + cx[7]));
  float sy = ((cy[0] + cy[1]) + (cy[2] + cy[3])) + ((cy[4] + cy[5]) + (cy[6] + cy[7]));
  sx += __shfl_xor(sx, 32);
  sy += __shfl_xor(sy, 32);
  float2 self = bf2f2(xw1s2[(size_t)node * 32 + l]);
  float2 bb = ((const float2*)b1)[l];
  float vx = dd * (sx + dd * self.x) + bb.x;
  float vy = dd * (sy + dd * self.y) + bb.y;
  vx = vx > 0.f ? vx : 0.f;
  vy = vy > 0.f ? vy : 0.f;
  int c = lane & 31;
  float p = 0.f;
#pragma unroll
  for (int kk = 0; kk < 32; kk++) {
    int k = h * 32 + kk;
    float hv = (k & 1) ? __shfl(vy, k >> 1) : __shfl(vx, k >> 1);
    p += hv * w2s[k * N_CLS + c];
  }
  p += __shfl_xor(p, 32);
  if (lane < 32) xw2s[(size_t)node * N_CLS + c] = f2bf(p * dd);
}

// ---------- agg2 + log_softmax ----------
__global__ __launch_bounds__(256) void k_agg2(const unsigned* __restrict__ xw2s2,
    const int* __restrict__ rowptr, const int* __restrict__ csr_src,
    const float* __restrict__ dinv, const float* __restrict__ b2,
    float* __restrict__ out) {
  int wave = threadIdx.x >> 6;
  int lane = threadIdx.x & 63;
  int q = lane >> 4, l = lane & 15;
  int node = blockIdx.x * 4 + wave;
  float dd = dinv[node];
  int beg = rowptr[node], end = rowptr[node + 1];
  float cx[4], cy[4];
#pragma unroll
  for (int j = 0; j < 4; j++) { cx[j] = 0.f; cy[j] = 0.f; }
  for (int e = beg + q; e < end; e += 16) {
    int idx[4]; bool val[4];
#pragma unroll
    for (int j = 0; j < 4; j++) {
      int ee = e + 4 * j;
      val[j] = ee < end;
      idx[j] = csr_src[val[j] ? ee : beg];
    }
#pragma unroll
    for (int j = 0; j < 4; j++) {
      float2 v = bf2f2(xw2s2[(size_t)idx[j] * 16 + l]);
      cx[j] += val[j] ? v.x : 0.f;
      cy[j] += val[j] ? v.y : 0.f;
    }
  }
  float sx = (cx[0] + cx[1]) + (cx[2] + cx[3]);
  float sy = (cy[0] + cy[1]) + (cy[2] + cy[3]);
  sx += __shfl_xor(sx, 32); sy += __shfl_xor(sy, 32);
  sx += __shfl_xor(sx, 16); sy += __shfl_xor(sy, 16);
  float2 self = bf2f2(xw2s2[(size_t)node * 16 + l]);
  float2 bb = ((const float2*)b2)[l];
  float lx = dd * (sx + self.x) + bb.x;
  float ly = dd * (sy + self.y) + bb.y;
  float m = fmaxf(lx, ly);
#pragma unroll
  for (int o = 8; o > 0; o >>= 1) m = fmaxf(m, __shfl_xor(m, o));
  float s2 = __expf(lx - m) + __expf(ly - m);
#pragma unroll
  for (int o = 8; o > 0; o >>= 1) s2 += __shfl_xor(s2, o);
  float lse = m + __logf(s2);
  if (lane < 16)
    ((float2*)out)[(size_t)node * 16 + l] = make_float2(lx - lse, ly - lse);
}

extern "C" void kernel_launch(void* const* d_in, const int* in_sizes, int n_in,
                              void* d_out, int out_size, void* d_ws, size_t ws_size,
                              hipStream_t stream) {
  (void)n_in; (void)out_size; (void)ws_size;
  const float* x  = (const float*)d_in[0];
  const int*   ei = (const int*)d_in[1];
  const float* w1 = (const float*)d_in[2];
  const float* b1 = (const float*)d_in[3];
  const float* w2 = (const float*)d_in[4];
  const float* b2 = (const float*)d_in[5];
  float* out = (float*)d_out;
  int e = in_sizes[1] / 2;
  const int* src = ei;
  const int* dst = ei + e;

  char* ws = (char*)d_ws;
  int* H              = (int*)(ws + 0x0000000);           // 256KB (block-major)
  int* Hs             = (int*)(ws + 0x0040000);           // 256KB (bin-major, scanned)
  int* btot           = (int*)(ws + 0x0080000);           // 1KB
  int* btoff          = (int*)(ws + 0x0080400);           // 1KB
  int* rowptr         = (int*)(ws + 0x0081000);           // 256KB + 4
  float* dinv         = (float*)(ws + 0x00D0000);         // 256KB
  unsigned* pk        = (unsigned*)(ws + 0x0200000);      // 4MB (bucket-sorted packed edges)
  int* csr_src        = (int*)(ws + 0x0600000);           // 4MB
  unsigned short* w1t = (unsigned short*)(ws + 0x0A00000);// 128KB
  unsigned short* xw1s= (unsigned short*)(ws + 0x0A20000);// 8MB (bf16, UNSCALED)
  unsigned short* xw2s= (unsigned short*)(ws + 0x1220000);// 4MB (bf16)

  int e4 = e / 4;
  k_hist_w1t  <<<NSB + 256, 256, 0, stream>>>(dst, H, w1, w1t, e4);
  k_scan_bin  <<<NBUK, 256, 0, stream>>>(H, Hs, btot);
  k_scan_tot  <<<1, 256, 0, stream>>>(btot, btoff, rowptr, e);
  k_scatter   <<<NSB, 256, 0, stream>>>(dst, src, Hs, btoff, pk, e4);
  k_bucket_csr<<<NBUK, 256, 0, stream>>>(pk, btoff, btot, rowptr, csr_src, dinv);
  k_gemm1     <<<N_NODES / 32, 256, 0, stream>>>(x, w1t, xw1s);
  k_agg1      <<<N_NODES / 4, 256, 0, stream>>>((const unsigned*)xw1s, rowptr, csr_src,
                                                dinv, b1, w2, xw2s);
  k_agg2      <<<N_NODES / 4, 256, 0, stream>>>((const unsigned*)xw2s, rowptr, csr_src,
                                                dinv, b2, out);
}